// Round 5
// baseline (242.030 us; speedup 1.0000x reference)
//
#include <hip/hip_runtime.h>
#include <math.h>

#define NN 50000
#define NE 800000
#define D  128
#define SCAN_CHUNK 1024
#define NSCAN 49          // ceil(NN/SCAN_CHUNK)
#define PG_BLOCKS 782     // ceil((NE/4)/256)
#define NROLES 1564       // 782 count + 782 gemm
#define SSF_BLOCKS 832    // 49 scan + 783 scale (783*256 = 200448 >= NN*4)

typedef __attribute__((ext_vector_type(8))) short bf16x8;
typedef __attribute__((ext_vector_type(4))) float f32x4;

__device__ __forceinline__ unsigned short f32_to_bf16(float f) {
    unsigned u = __float_as_uint(f);
    u = u + 0x7FFFu + ((u >> 16) & 1u);   // RNE
    return (unsigned short)(u >> 16);
}

// fast tanh: 1 - 2*rcp(e^{2x}+1). Exact at saturation. |err| ~1e-6.
__device__ __forceinline__ float fast_tanh(float x) {
    float e = __expf(2.0f * x);
    return fmaf(-2.0f, __builtin_amdgcn_rcpf(e + 1.0f), 1.0f);
}

// ---- K0: deg/flag/flag2 zero; W bf16-frag pack (block 0); zb sentinel ------
__global__ __launch_bounds__(256) void k_init(
        const float* __restrict__ Wg, int* __restrict__ deg,
        int* __restrict__ flag, int* __restrict__ flag2,
        unsigned short* __restrict__ wpk, unsigned short* __restrict__ zb) {
    int tid = threadIdx.x;
    int idx = blockIdx.x * 256 + tid;

    if (idx < NN / 4) ((int4*)deg)[idx] = (int4){0, 0, 0, 0};
    if (idx == NN / 4) { *flag = 0; *flag2 = 0; }

    if (blockIdx.x == 0) {
        // frag = nt*256 + kt*64 + quad*16 + lo, elem j = k&7 (verified layout)
#pragma unroll 8
        for (int i = 0; i < 64; i++) {
            int o = i * 256 + tid;
            int j = o & 7, frag = o >> 3;
            int lo = frag & 15, quad = (frag >> 4) & 3;
            int kt = (frag >> 6) & 3, nt = frag >> 8;
            wpk[o] = f32_to_bf16(Wg[(kt * 32 + quad * 8 + j) * 128 + nt * 16 + lo]);
        }
    }
    if (blockIdx.x == 1 && tid < 64)
        ((unsigned*)(zb + (size_t)NN * D))[tid] = 0u;   // sentinel row = 0
}

// ---- K1: count-atomics blocks + GEMM blocks interleaved by parity.
// GEMM writes UNSCALED fp32 zf (no dinv dep) -> overlaps with atomics. ------
__global__ __launch_bounds__(256) void k_count_gemm(
        const float* __restrict__ h, const uint4* __restrict__ wpk4,
        const int* __restrict__ ei, int* __restrict__ deg,
        unsigned short* __restrict__ rank, float* __restrict__ zf,
        int* __restrict__ outtail, int tailN) {
    int tid = threadIdx.x;
    int bid = blockIdx.x;

    if (bid & 1) {
        int g = (bid >> 1) * 256 + tid;
        if (g < NE / 4) {
            int4 d4 = ((const int4*)(ei + NE))[g];
            ushort4 r;
            r.x = (unsigned short)atomicAdd(&deg[d4.x], 1);
            r.y = (unsigned short)atomicAdd(&deg[d4.y], 1);
            r.z = (unsigned short)atomicAdd(&deg[d4.z], 1);
            r.w = (unsigned short)atomicAdd(&deg[d4.w], 1);
            ((ushort4*)rank)[g] = r;
        }
        for (int i = g; i < tailN; i += PG_BLOCKS * 256) outtail[i] = 0;
        return;
    }

    int gid = bid >> 1;
    int w = tid >> 6, lane = tid & 63;
    int quad = lane >> 4, lo = lane & 15;
    int rowBase = gid * 64 + w * 16;
    int rowA = rowBase + lo; if (rowA > NN - 1) rowA = NN - 1;
    const float4* h4 = (const float4*)h;

    bf16x8 af[4];
#pragma unroll
    for (int kt = 0; kt < 4; kt++) {
        float4 u = h4[(size_t)rowA * 32 + kt * 8 + quad * 2];
        float4 v = h4[(size_t)rowA * 32 + kt * 8 + quad * 2 + 1];
        bf16x8 a;
        a[0] = (short)f32_to_bf16(u.x); a[1] = (short)f32_to_bf16(u.y);
        a[2] = (short)f32_to_bf16(u.z); a[3] = (short)f32_to_bf16(u.w);
        a[4] = (short)f32_to_bf16(v.x); a[5] = (short)f32_to_bf16(v.y);
        a[6] = (short)f32_to_bf16(v.z); a[7] = (short)f32_to_bf16(v.w);
        af[kt] = a;
    }

    f32x4 acc[8];
#pragma unroll
    for (int nt = 0; nt < 8; nt++) acc[nt] = (f32x4){0.f, 0.f, 0.f, 0.f};

#pragma unroll
    for (int kt = 0; kt < 4; kt++)
#pragma unroll
        for (int nt = 0; nt < 8; nt++) {
            uint4 tb = wpk4[nt * 256 + kt * 64 + lane];   // coalesced, L1-hit
            acc[nt] = __builtin_amdgcn_mfma_f32_16x16x32_bf16(
                af[kt], __builtin_bit_cast(bf16x8, tb), acc[nt], 0, 0, 0);
        }

#pragma unroll
    for (int reg = 0; reg < 4; reg++) {
        int row = rowBase + quad * 4 + reg;
        if (row < NN) {
#pragma unroll
            for (int nt = 0; nt < 8; nt++)
                zf[(size_t)row * D + nt * 16 + lo] = acc[nt][reg];
        }
    }
}

// ---- K2: scan(blocks 0-48) || zb-scale(blocks 49+), then flag2 barrier,
// then CSR fill by all blocks. rowoff crosses XCDs within this kernel ->
// agent-scope atomics both sides (per-XCD L2 non-coherence). ----------------
__global__ __launch_bounds__(256) void k_scan_scale_fill(
        const int* __restrict__ deg, int* __restrict__ partial,
        int* __restrict__ flag, int* __restrict__ flag2,
        int* __restrict__ rowoff, float* __restrict__ dinv,
        const float* __restrict__ zf, unsigned short* __restrict__ zb,
        const int* __restrict__ ei, const unsigned short* __restrict__ rank,
        int* __restrict__ csr) {
    __shared__ int wsum[4];
    int tid = threadIdx.x;
    int bid = blockIdx.x;

    if (bid < NSCAN) {
        // ---------------- scan role (proven structure) ----------------
        int lane = tid & 63, wv = tid >> 6;
        int base = bid * SCAN_CHUNK + tid * 4;
        int d[4]; int s = 0;
#pragma unroll
        for (int j = 0; j < 4; j++) {
            int i = base + j;
            d[j] = 0;
            if (i < NN) {
                d[j] = deg[i];
                s += d[j];
                dinv[i] = rsqrtf((float)d[j] + 1.0f);   // +1 self loop
            }
        }
        int v = s;
#pragma unroll
        for (int off = 1; off < 64; off <<= 1) {
            int u = __shfl_up(v, off, 64);
            if (lane >= off) v += u;
        }
        if (lane == 63) wsum[wv] = v;
        __syncthreads();
        int add = 0;
#pragma unroll
        for (int k = 0; k < 4; k++) if (k < wv) add += wsum[k];
        int inc = v + add;
        if (tid == 255) {
            atomicExch(&partial[bid], inc);
            __threadfence();
            atomicAdd(flag, 1);
            while (atomicAdd(flag, 0) < NSCAN) {}   // 49 blocks co-resident
        }
        __syncthreads();
        int pv = (lane < NSCAN && lane < bid) ? atomicAdd(&partial[lane], 0) : 0;
#pragma unroll
        for (int off = 32; off > 0; off >>= 1) pv += __shfl_xor(pv, off, 64);
        int ex = inc - s + pv;
#pragma unroll
        for (int j = 0; j < 4; j++) {
            int i = base + j;
            if (i < NN) {
                __hip_atomic_store(&rowoff[i], ex, __ATOMIC_RELAXED,
                                   __HIP_MEMORY_SCOPE_AGENT);
                ex += d[j];
                if (i == NN - 1)
                    __hip_atomic_store(&rowoff[NN], ex, __ATOMIC_RELAXED,
                                       __HIP_MEMORY_SCOPE_AGENT);
            }
        }
        __syncthreads();
        if (tid == 0)
            __hip_atomic_fetch_add(flag2, 1, __ATOMIC_RELEASE,
                                   __HIP_MEMORY_SCOPE_AGENT);
    } else {
        // ------- scale role: zb = bf16(zf * rsqrt(deg+1)), bit-identical ----
        int g = (bid - NSCAN) * 256 + tid;
        if (g < NN * 4) {
            int row = g >> 2, seg = g & 3;
            float dn = rsqrtf((float)deg[row] + 1.0f);
            const float4* src = (const float4*)(zf + (size_t)row * D + seg * 32);
            uint4* dst = (uint4*)(zb + (size_t)row * D + seg * 32);
#pragma unroll
            for (int i = 0; i < 4; i++) {
                float4 a = src[i * 2], bb = src[i * 2 + 1];
                uint4 o;
                o.x = (unsigned)f32_to_bf16(a.x * dn) | ((unsigned)f32_to_bf16(a.y * dn) << 16);
                o.y = (unsigned)f32_to_bf16(a.z * dn) | ((unsigned)f32_to_bf16(a.w * dn) << 16);
                o.z = (unsigned)f32_to_bf16(bb.x * dn) | ((unsigned)f32_to_bf16(bb.y * dn) << 16);
                o.w = (unsigned)f32_to_bf16(bb.z * dn) | ((unsigned)f32_to_bf16(bb.w * dn) << 16);
                dst[i] = o;
            }
        }
    }

    // ---------------- barrier: wait for all 49 scan blocks ----------------
    if (tid == 0) {
        while (__hip_atomic_load(flag2, __ATOMIC_ACQUIRE,
                                 __HIP_MEMORY_SCOPE_AGENT) < NSCAN)
            __builtin_amdgcn_s_sleep(2);
    }
    __syncthreads();

    // ---------------- CSR fill (agent-scope rowoff reads) -----------------
    for (int g = bid * 256 + tid; g < NE / 4; g += SSF_BLOCKS * 256) {
        int4 s4 = ((const int4*)ei)[g];
        int4 d4 = ((const int4*)(ei + NE))[g];
        ushort4 r4 = ((const ushort4*)rank)[g];
        int ox = __hip_atomic_load(&rowoff[d4.x], __ATOMIC_RELAXED, __HIP_MEMORY_SCOPE_AGENT);
        int oy = __hip_atomic_load(&rowoff[d4.y], __ATOMIC_RELAXED, __HIP_MEMORY_SCOPE_AGENT);
        int oz = __hip_atomic_load(&rowoff[d4.z], __ATOMIC_RELAXED, __HIP_MEMORY_SCOPE_AGENT);
        int ow = __hip_atomic_load(&rowoff[d4.w], __ATOMIC_RELAXED, __HIP_MEMORY_SCOPE_AGENT);
        csr[ox + r4.x] = s4.x;
        csr[oy + r4.y] = s4.y;
        csr[oz + r4.z] = s4.z;
        csr[ow + r4.w] = s4.w;
    }
}

// ---- K3: weightless gather + LN + tanh (unchanged, verified) --------------
__global__ __launch_bounds__(256) void k_gather_ln(
        const int* __restrict__ rowoff, const int* __restrict__ csr,
        const float* __restrict__ dinv, const unsigned* __restrict__ zbu,
        const float* __restrict__ bias, const float* __restrict__ gamma,
        const float* __restrict__ beta, float* __restrict__ out) {
    int tid = threadIdx.x;
    int w = tid >> 6, lane = tid & 63;
    int rowBase = blockIdx.x * 16 + w * 4;

    int cs[4], ce[4]; float dn[4]; unsigned selfz[4]; int v0[4];
#pragma unroll
    for (int r = 0; r < 4; r++) {
        int row = rowBase + r;
        cs[r] = __builtin_amdgcn_readfirstlane(rowoff[row]);
        ce[r] = __builtin_amdgcn_readfirstlane(rowoff[row + 1]);
        dn[r] = dinv[row];
        selfz[r] = zbu[(size_t)row * 64 + lane];
    }
#pragma unroll
    for (int r = 0; r < 4; r++) {
        int m0 = ce[r] - cs[r]; if (m0 > 64) m0 = 64;
        int t0 = csr[cs[r] + lane];          // csr padded +64: in-bounds
        v0[r] = (lane < m0) ? t0 : NN;       // pad -> zero sentinel row
    }

    float2 x[4];
#pragma unroll
    for (int r = 0; r < 4; r++) {
        float ax = __uint_as_float(selfz[r] << 16);
        float ay = __uint_as_float(selfz[r] & 0xFFFF0000u);
        int c = cs[r];
        int v = v0[r];
        while (true) {
            int m = ce[r] - c; if (m > 64) m = 64;
            int nb = (m + 15) >> 4;
            for (int jb = 0; jb < nb; ++jb) {
                int j = jb << 4;
                unsigned p[16];
#pragma unroll
                for (int q = 0; q < 16; q++) {
                    int sq = __builtin_amdgcn_readlane(v, j + q);
                    p[q] = zbu[(size_t)sq * 64 + lane];
                }
#pragma unroll
                for (int q = 0; q < 16; q++) {
                    ax += __uint_as_float(p[q] << 16);
                    ay += __uint_as_float(p[q] & 0xFFFF0000u);
                }
            }
            c += 64;
            if (c >= ce[r]) break;
            int m2 = ce[r] - c; if (m2 > 64) m2 = 64;
            int t2 = csr[c + lane];
            v = (lane < m2) ? t2 : NN;
        }
        x[r].x = ax * dn[r];
        x[r].y = ay * dn[r];
    }

    float2 bi = ((const float2*)bias)[lane];
    float2 ga = ((const float2*)gamma)[lane];
    float2 be = ((const float2*)beta)[lane];
#pragma unroll
    for (int r = 0; r < 4; r++) {
        int row = rowBase + r;
        float y0 = x[r].x + bi.x;
        float y1 = x[r].y + bi.y;
        float s = y0 + y1;
#pragma unroll
        for (int off = 32; off > 0; off >>= 1) s += __shfl_xor(s, off, 64);
        float m = s * (1.0f / 128.0f);
        float v0f = y0 - m, v1f = y1 - m;
        float vs = v0f * v0f + v1f * v1f;
#pragma unroll
        for (int off = 32; off > 0; off >>= 1) vs += __shfl_xor(vs, off, 64);
        float rstd = rsqrtf(vs * (1.0f / 128.0f) + 1e-5f);
        float2 o;
        o.x = fast_tanh(v0f * rstd * ga.x + be.x);
        o.y = fast_tanh(v1f * rstd * ga.y + be.y);
        *(float2*)&out[(size_t)row * D + lane * 2] = o;
    }
}

extern "C" void kernel_launch(void* const* d_in, const int* in_sizes, int n_in,
                              void* d_out, int out_size, void* d_ws, size_t ws_size,
                              hipStream_t stream) {
    // inputs: t, h, edge_index, batch_size, W, b, gamma, beta
    const float* h     = (const float*)d_in[1];
    const int*   ei    = (const int*)  d_in[2];
    const float* Wg    = (const float*)d_in[4];
    const float* b     = (const float*)d_in[5];
    const float* gamma = (const float*)d_in[6];
    const float* beta  = (const float*)d_in[7];
    float* out = (float*)d_out;

    // workspace layout (~44.5 MB). csr has +64-int pad (branchless chunk loads).
    char* wsb = (char*)d_ws;
    unsigned short* wpk    = (unsigned short*)(wsb);            // 32768 B
    int*            deg    = (int*)(wsb + 32768);               // NN ints
    int*            flag   = (int*)(wsb + 232768);              // 1 int
    int*            flag2  = (int*)(wsb + 232772);              // 1 int
    int*            partial= (int*)(wsb + 232832);              // 64 ints
    unsigned short* rank   = (unsigned short*)(wsb + 233088);   // NE ushorts
    int*            rowoff = (int*)(wsb + 1833088);             // NN+1 ints
    float*          dinv   = (float*)(wsb + 2633152);           // NN floats
    int*            csr    = (int*)(wsb + 2833152);             // NE ints + 64 pad
    unsigned short* zb     = (unsigned short*)(wsb + 6033408);  // (NN+1)*128 ushorts
    float*          zf     = (float*)(wsb + 18833664);          // NN*128 floats

    int tailN = out_size - NN * D;                 // int-zeros tail of d_out
    int* outtail = (int*)(out + (size_t)NN * D);

    k_init          <<<64,         256, 0, stream>>>(Wg, deg, flag, flag2, wpk, zb);
    k_count_gemm    <<<NROLES,     256, 0, stream>>>(h, (const uint4*)wpk, ei, deg, rank, zf, outtail, tailN);
    k_scan_scale_fill<<<SSF_BLOCKS,256, 0, stream>>>(deg, partial, flag, flag2, rowoff, dinv, zf, zb, ei, rank, csr);
    k_gather_ln     <<<NN / 16,    256, 0, stream>>>(rowoff, csr, dinv, (const unsigned*)zb, b, gamma, beta, out);
}

// Round 6
// 189.798 us; speedup vs baseline: 1.2752x; 1.2752x over previous
//
#include <hip/hip_runtime.h>
#include <math.h>

#define NN 50000
#define NE 800000
#define D  128
#define SCAN_CHUNK 1024
#define NSCAN 49          // ceil(NN/SCAN_CHUNK)
#define PG_BLOCKS 782     // ceil((NE/4)/256)
#define NROLES 1564       // 782 count + 782 gemm
#define SS_BLOCKS 832     // 49 scan + 783 scale (783*256 = 200448 >= NN*4)

typedef __attribute__((ext_vector_type(8))) short bf16x8;
typedef __attribute__((ext_vector_type(4))) float f32x4;

__device__ __forceinline__ unsigned short f32_to_bf16(float f) {
    unsigned u = __float_as_uint(f);
    u = u + 0x7FFFu + ((u >> 16) & 1u);   // RNE
    return (unsigned short)(u >> 16);
}

// fast tanh: 1 - 2*rcp(e^{2x}+1). Exact at saturation. |err| ~1e-6.
__device__ __forceinline__ float fast_tanh(float x) {
    float e = __expf(2.0f * x);
    return fmaf(-2.0f, __builtin_amdgcn_rcpf(e + 1.0f), 1.0f);
}

// ---- K0: deg/flag zero; W bf16-frag pack (block 0); zb sentinel row --------
__global__ __launch_bounds__(256) void k_init(
        const float* __restrict__ Wg, int* __restrict__ deg,
        int* __restrict__ flag, unsigned short* __restrict__ wpk,
        unsigned short* __restrict__ zb) {
    int tid = threadIdx.x;
    int idx = blockIdx.x * 256 + tid;

    if (idx < NN / 4) ((int4*)deg)[idx] = (int4){0, 0, 0, 0};
    if (idx == NN / 4) *flag = 0;

    if (blockIdx.x == 0) {
        // frag = nt*256 + kt*64 + quad*16 + lo, elem j = k&7 (verified layout)
#pragma unroll 8
        for (int i = 0; i < 64; i++) {
            int o = i * 256 + tid;
            int j = o & 7, frag = o >> 3;
            int lo = frag & 15, quad = (frag >> 4) & 3;
            int kt = (frag >> 6) & 3, nt = frag >> 8;
            wpk[o] = f32_to_bf16(Wg[(kt * 32 + quad * 8 + j) * 128 + nt * 16 + lo]);
        }
    }
    if (blockIdx.x == 1 && tid < 64)
        ((unsigned*)(zb + (size_t)NN * D))[tid] = 0u;   // sentinel row = 0
}

// ---- K1: count-atomics blocks + GEMM blocks interleaved by parity.
// GEMM writes UNSCALED fp32 zf (no dinv dep) -> overlaps with atomics. ------
__global__ __launch_bounds__(256) void k_count_gemm(
        const float* __restrict__ h, const uint4* __restrict__ wpk4,
        const int* __restrict__ ei, int* __restrict__ deg,
        unsigned short* __restrict__ rank, float* __restrict__ zf,
        int* __restrict__ outtail, int tailN) {
    int tid = threadIdx.x;
    int bid = blockIdx.x;

    if (bid & 1) {
        int g = (bid >> 1) * 256 + tid;
        if (g < NE / 4) {
            int4 d4 = ((const int4*)(ei + NE))[g];
            ushort4 r;
            r.x = (unsigned short)atomicAdd(&deg[d4.x], 1);
            r.y = (unsigned short)atomicAdd(&deg[d4.y], 1);
            r.z = (unsigned short)atomicAdd(&deg[d4.z], 1);
            r.w = (unsigned short)atomicAdd(&deg[d4.w], 1);
            ((ushort4*)rank)[g] = r;
        }
        for (int i = g; i < tailN; i += PG_BLOCKS * 256) outtail[i] = 0;
        return;
    }

    int gid = bid >> 1;
    int w = tid >> 6, lane = tid & 63;
    int quad = lane >> 4, lo = lane & 15;
    int rowBase = gid * 64 + w * 16;
    int rowA = rowBase + lo; if (rowA > NN - 1) rowA = NN - 1;
    const float4* h4 = (const float4*)h;

    bf16x8 af[4];
#pragma unroll
    for (int kt = 0; kt < 4; kt++) {
        float4 u = h4[(size_t)rowA * 32 + kt * 8 + quad * 2];
        float4 v = h4[(size_t)rowA * 32 + kt * 8 + quad * 2 + 1];
        bf16x8 a;
        a[0] = (short)f32_to_bf16(u.x); a[1] = (short)f32_to_bf16(u.y);
        a[2] = (short)f32_to_bf16(u.z); a[3] = (short)f32_to_bf16(u.w);
        a[4] = (short)f32_to_bf16(v.x); a[5] = (short)f32_to_bf16(v.y);
        a[6] = (short)f32_to_bf16(v.z); a[7] = (short)f32_to_bf16(v.w);
        af[kt] = a;
    }

    f32x4 acc[8];
#pragma unroll
    for (int nt = 0; nt < 8; nt++) acc[nt] = (f32x4){0.f, 0.f, 0.f, 0.f};

#pragma unroll
    for (int kt = 0; kt < 4; kt++)
#pragma unroll
        for (int nt = 0; nt < 8; nt++) {
            uint4 tb = wpk4[nt * 256 + kt * 64 + lane];   // coalesced, L1-hit
            acc[nt] = __builtin_amdgcn_mfma_f32_16x16x32_bf16(
                af[kt], __builtin_bit_cast(bf16x8, tb), acc[nt], 0, 0, 0);
        }

#pragma unroll
    for (int reg = 0; reg < 4; reg++) {
        int row = rowBase + quad * 4 + reg;
        if (row < NN) {
#pragma unroll
            for (int nt = 0; nt < 8; nt++)
                zf[(size_t)row * D + nt * 16 + lo] = acc[nt][reg];
        }
    }
}

// ---- K2: scan(blocks 0-48) || zb-scale(blocks 49+). NO cross-block deps:
// scale recomputes dinv inline from deg (bit-identical). Kernel boundary
// (not an in-kernel barrier) publishes rowoff to K3 — round-5 lesson. -------
__global__ __launch_bounds__(256) void k_scan_scale(
        const int* __restrict__ deg, int* __restrict__ partial,
        int* __restrict__ flag, int* __restrict__ rowoff,
        float* __restrict__ dinv, const float* __restrict__ zf,
        unsigned short* __restrict__ zb) {
    __shared__ int wsum[4];
    int tid = threadIdx.x;
    int bid = blockIdx.x;

    if (bid < NSCAN) {
        // ---------------- scan role (proven structure) ----------------
        int lane = tid & 63, wv = tid >> 6;
        int base = bid * SCAN_CHUNK + tid * 4;
        int d[4]; int s = 0;
#pragma unroll
        for (int j = 0; j < 4; j++) {
            int i = base + j;
            d[j] = 0;
            if (i < NN) {
                d[j] = deg[i];
                s += d[j];
                dinv[i] = rsqrtf((float)d[j] + 1.0f);   // +1 self loop
            }
        }
        int v = s;
#pragma unroll
        for (int off = 1; off < 64; off <<= 1) {
            int u = __shfl_up(v, off, 64);
            if (lane >= off) v += u;
        }
        if (lane == 63) wsum[wv] = v;
        __syncthreads();
        int add = 0;
#pragma unroll
        for (int k = 0; k < 4; k++) if (k < wv) add += wsum[k];
        int inc = v + add;
        if (tid == 255) {
            atomicExch(&partial[bid], inc);
            __threadfence();
            atomicAdd(flag, 1);
            while (atomicAdd(flag, 0) < NSCAN) {}   // 49 spinners, co-resident
        }
        __syncthreads();
        int pv = (lane < NSCAN && lane < bid) ? atomicAdd(&partial[lane], 0) : 0;
#pragma unroll
        for (int off = 32; off > 0; off >>= 1) pv += __shfl_xor(pv, off, 64);
        int ex = inc - s + pv;
#pragma unroll
        for (int j = 0; j < 4; j++) {
            int i = base + j;
            if (i < NN) {
                rowoff[i] = ex;
                ex += d[j];
                if (i == NN - 1) rowoff[NN] = ex;   // sentinel = NE
            }
        }
    } else {
        // ------- scale role: zb = bf16(zf * rsqrt(deg+1)), bit-identical ----
        int g = (bid - NSCAN) * 256 + tid;
        if (g < NN * 4) {
            int row = g >> 2, seg = g & 3;
            float dn = rsqrtf((float)deg[row] + 1.0f);
            const float4* src = (const float4*)(zf + (size_t)row * D + seg * 32);
            uint4* dst = (uint4*)(zb + (size_t)row * D + seg * 32);
#pragma unroll
            for (int i = 0; i < 4; i++) {
                float4 a = src[i * 2], bb = src[i * 2 + 1];
                uint4 o;
                o.x = (unsigned)f32_to_bf16(a.x * dn) | ((unsigned)f32_to_bf16(a.y * dn) << 16);
                o.y = (unsigned)f32_to_bf16(a.z * dn) | ((unsigned)f32_to_bf16(a.w * dn) << 16);
                o.z = (unsigned)f32_to_bf16(bb.x * dn) | ((unsigned)f32_to_bf16(bb.y * dn) << 16);
                o.w = (unsigned)f32_to_bf16(bb.z * dn) | ((unsigned)f32_to_bf16(bb.w * dn) << 16);
                dst[i] = o;
            }
        }
    }
}

// ---- K3: CSR fill, plain cached loads (kernel boundary = coherence) -------
__global__ __launch_bounds__(320) void k_fill(const int* __restrict__ ei,
                                              const int* __restrict__ rowoff,
                                              const unsigned short* __restrict__ rank,
                                              int* __restrict__ csr) {
    int t = blockIdx.x * 320 + threadIdx.x;   // 625*320*4 = NE exactly
    int4 s4 = ((const int4*)ei)[t];
    int4 d4 = ((const int4*)(ei + NE))[t];
    ushort4 r4 = ((const ushort4*)rank)[t];
    csr[rowoff[d4.x] + r4.x] = s4.x;
    csr[rowoff[d4.y] + r4.y] = s4.y;
    csr[rowoff[d4.z] + r4.z] = s4.z;
    csr[rowoff[d4.w] + r4.w] = s4.w;
}

// ---- K4: weightless gather + LN + tanh (unchanged, verified) --------------
__global__ __launch_bounds__(256) void k_gather_ln(
        const int* __restrict__ rowoff, const int* __restrict__ csr,
        const float* __restrict__ dinv, const unsigned* __restrict__ zbu,
        const float* __restrict__ bias, const float* __restrict__ gamma,
        const float* __restrict__ beta, float* __restrict__ out) {
    int tid = threadIdx.x;
    int w = tid >> 6, lane = tid & 63;
    int rowBase = blockIdx.x * 16 + w * 4;

    int cs[4], ce[4]; float dn[4]; unsigned selfz[4]; int v0[4];
#pragma unroll
    for (int r = 0; r < 4; r++) {
        int row = rowBase + r;
        cs[r] = __builtin_amdgcn_readfirstlane(rowoff[row]);
        ce[r] = __builtin_amdgcn_readfirstlane(rowoff[row + 1]);
        dn[r] = dinv[row];
        selfz[r] = zbu[(size_t)row * 64 + lane];
    }
#pragma unroll
    for (int r = 0; r < 4; r++) {
        int m0 = ce[r] - cs[r]; if (m0 > 64) m0 = 64;
        int t0 = csr[cs[r] + lane];          // csr padded +64: in-bounds
        v0[r] = (lane < m0) ? t0 : NN;       // pad -> zero sentinel row
    }

    float2 x[4];
#pragma unroll
    for (int r = 0; r < 4; r++) {
        float ax = __uint_as_float(selfz[r] << 16);
        float ay = __uint_as_float(selfz[r] & 0xFFFF0000u);
        int c = cs[r];
        int v = v0[r];
        while (true) {
            int m = ce[r] - c; if (m > 64) m = 64;
            int nb = (m + 15) >> 4;
            for (int jb = 0; jb < nb; ++jb) {
                int j = jb << 4;
                unsigned p[16];
#pragma unroll
                for (int q = 0; q < 16; q++) {
                    int sq = __builtin_amdgcn_readlane(v, j + q);
                    p[q] = zbu[(size_t)sq * 64 + lane];
                }
#pragma unroll
                for (int q = 0; q < 16; q++) {
                    ax += __uint_as_float(p[q] << 16);
                    ay += __uint_as_float(p[q] & 0xFFFF0000u);
                }
            }
            c += 64;
            if (c >= ce[r]) break;
            int m2 = ce[r] - c; if (m2 > 64) m2 = 64;
            int t2 = csr[c + lane];
            v = (lane < m2) ? t2 : NN;
        }
        x[r].x = ax * dn[r];
        x[r].y = ay * dn[r];
    }

    float2 bi = ((const float2*)bias)[lane];
    float2 ga = ((const float2*)gamma)[lane];
    float2 be = ((const float2*)beta)[lane];
#pragma unroll
    for (int r = 0; r < 4; r++) {
        int row = rowBase + r;
        float y0 = x[r].x + bi.x;
        float y1 = x[r].y + bi.y;
        float s = y0 + y1;
#pragma unroll
        for (int off = 32; off > 0; off >>= 1) s += __shfl_xor(s, off, 64);
        float m = s * (1.0f / 128.0f);
        float v0f = y0 - m, v1f = y1 - m;
        float vs = v0f * v0f + v1f * v1f;
#pragma unroll
        for (int off = 32; off > 0; off >>= 1) vs += __shfl_xor(vs, off, 64);
        float rstd = rsqrtf(vs * (1.0f / 128.0f) + 1e-5f);
        float2 o;
        o.x = fast_tanh(v0f * rstd * ga.x + be.x);
        o.y = fast_tanh(v1f * rstd * ga.y + be.y);
        *(float2*)&out[(size_t)row * D + lane * 2] = o;
    }
}

extern "C" void kernel_launch(void* const* d_in, const int* in_sizes, int n_in,
                              void* d_out, int out_size, void* d_ws, size_t ws_size,
                              hipStream_t stream) {
    // inputs: t, h, edge_index, batch_size, W, b, gamma, beta
    const float* h     = (const float*)d_in[1];
    const int*   ei    = (const int*)  d_in[2];
    const float* Wg    = (const float*)d_in[4];
    const float* b     = (const float*)d_in[5];
    const float* gamma = (const float*)d_in[6];
    const float* beta  = (const float*)d_in[7];
    float* out = (float*)d_out;

    // workspace layout (~44.5 MB). csr has +64-int pad (branchless chunk loads).
    char* wsb = (char*)d_ws;
    unsigned short* wpk    = (unsigned short*)(wsb);            // 32768 B
    int*            deg    = (int*)(wsb + 32768);               // NN ints
    int*            flag   = (int*)(wsb + 232768);              // 1 int
    int*            partial= (int*)(wsb + 232832);              // 64 ints
    unsigned short* rank   = (unsigned short*)(wsb + 233088);   // NE ushorts
    int*            rowoff = (int*)(wsb + 1833088);             // NN+1 ints
    float*          dinv   = (float*)(wsb + 2633152);           // NN floats
    int*            csr    = (int*)(wsb + 2833152);             // NE ints + 64 pad
    unsigned short* zb     = (unsigned short*)(wsb + 6033408);  // (NN+1)*128 ushorts
    float*          zf     = (float*)(wsb + 18833664);          // NN*128 floats

    int tailN = out_size - NN * D;                 // int-zeros tail of d_out
    int* outtail = (int*)(out + (size_t)NN * D);

    k_init       <<<64,        256, 0, stream>>>(Wg, deg, flag, wpk, zb);
    k_count_gemm <<<NROLES,    256, 0, stream>>>(h, (const uint4*)wpk, ei, deg, rank, zf, outtail, tailN);
    k_scan_scale <<<SS_BLOCKS, 256, 0, stream>>>(deg, partial, flag, rowoff, dinv, zf, zb);
    k_fill       <<<625,       320, 0, stream>>>(ei, rowoff, rank, csr);
    k_gather_ln  <<<NN / 16,   256, 0, stream>>>(rowoff, csr, dinv, (const unsigned*)zb, b, gamma, beta, out);
}